// Round 1
// baseline (556.926 us; speedup 1.0000x reference)
//
#include <hip/hip_runtime.h>

// ---------------------------------------------------------------------------
// GCN 2-layer forward: out = relu(A_hat @ relu(A_hat @ (X W1) + b1) W2 + b2)
// A_hat = D^-1/2 (A + I) D^-1/2, built per-call as CSR (by dst) in d_ws.
// ---------------------------------------------------------------------------

__global__ void deg_kernel(const int* __restrict__ dst, int E, int* __restrict__ deg) {
    int i = blockIdx.x * blockDim.x + threadIdx.x;
    if (i < E) atomicAdd(&deg[dst[i]], 1);
}

__global__ void dinv_kernel(const int* __restrict__ deg, float* __restrict__ dinv, int N) {
    int i = blockIdx.x * blockDim.x + threadIdx.x;
    if (i < N) dinv[i] = rsqrtf((float)(deg[i] + 1));  // +1 = self loop
}

// ---- exclusive scan of deg[N] -> row_ptr[N+1] (3 kernels) ----
__global__ void scan_partial(const int* __restrict__ deg, int N, int* __restrict__ blockSums) {
    __shared__ int sdata[256];
    int tid = threadIdx.x;
    int base = blockIdx.x * 1024;
    int sum = 0;
    for (int j = tid; j < 1024; j += 256) {
        int i = base + j;
        sum += (i < N) ? deg[i] : 0;
    }
    sdata[tid] = sum; __syncthreads();
    for (int off = 128; off > 0; off >>= 1) {
        if (tid < off) sdata[tid] += sdata[tid + off];
        __syncthreads();
    }
    if (tid == 0) blockSums[blockIdx.x] = sdata[0];
}

__global__ void scan_blocksums(int* __restrict__ blockSums, int n) {
    if (blockIdx.x == 0 && threadIdx.x == 0) {
        int acc = 0;
        for (int i = 0; i < n; i++) { int v = blockSums[i]; blockSums[i] = acc; acc += v; }
        blockSums[n] = acc;
    }
}

__global__ void scan_final(const int* __restrict__ deg, int N,
                           const int* __restrict__ blockSums,
                           int* __restrict__ row_ptr, int* __restrict__ cursor, int E) {
    __shared__ int sdata[256];
    int tid = threadIdx.x;
    int base = blockIdx.x * 1024;
    int carry = blockSums[blockIdx.x];
    int idx0 = base + tid * 4;
    int v[4]; int s = 0;
    #pragma unroll
    for (int q = 0; q < 4; q++) { int i = idx0 + q; v[q] = (i < N) ? deg[i] : 0; s += v[q]; }
    sdata[tid] = s; __syncthreads();
    for (int off = 1; off < 256; off <<= 1) {
        int t = (tid >= off) ? sdata[tid - off] : 0;
        __syncthreads();
        sdata[tid] += t;
        __syncthreads();
    }
    int excl = sdata[tid] - s + carry;
    #pragma unroll
    for (int q = 0; q < 4; q++) {
        int i = idx0 + q;
        if (i < N) { row_ptr[i] = excl; cursor[i] = excl; }
        excl += v[q];
    }
    if (blockIdx.x == 0 && tid == 0) row_ptr[N] = E;
}

__global__ void fill_csr(const int* __restrict__ src, const int* __restrict__ dst, int E,
                         const float* __restrict__ dinv, int* __restrict__ cursor,
                         int* __restrict__ csr_src, float* __restrict__ csr_w) {
    int i = blockIdx.x * blockDim.x + threadIdx.x;
    if (i < E) {
        int s = src[i], d = dst[i];
        int pos = atomicAdd(&cursor[d], 1);
        csr_src[pos] = s;
        csr_w[pos] = dinv[s] * dinv[d];
    }
}

// ---- fp32 GEMM: Y[N,COLS] = X[N,128] @ W[128,COLS], 4x4 register tile ----
template <int COLS>
__global__ __launch_bounds__(256) void gemm_kernel(const float* __restrict__ X,
                                                   const float* __restrict__ W,
                                                   float* __restrict__ Y, int N) {
    constexpr int CT = COLS / 4;       // threads along cols
    constexpr int RT = 256 / CT;       // threads along rows
    constexpr int ROWS = RT * 4;       // rows per block
    constexpr int LDT = ROWS + 4;      // pad keeps 16B alignment + spreads banks
    __shared__ float xT[128 * LDT];    // x transposed: [k][r]

    int tid = threadIdx.x;
    int row0 = blockIdx.x * ROWS;
    int kk = tid & 127;
    for (int rr = tid >> 7; rr < ROWS; rr += 2) {
        int r = row0 + rr;
        xT[kk * LDT + rr] = (r < N) ? X[(size_t)r * 128 + kk] : 0.0f;
    }
    __syncthreads();

    int ct = tid % CT, rt = tid / CT;
    int c0 = ct * 4, r0 = rt * 4;
    float acc[4][4] = {};
    #pragma unroll 4
    for (int k = 0; k < 128; k++) {
        float4 xv = *(const float4*)&xT[k * LDT + r0];
        float4 wv = *(const float4*)&W[(size_t)k * COLS + c0];
        float xs[4] = {xv.x, xv.y, xv.z, xv.w};
        float ws[4] = {wv.x, wv.y, wv.z, wv.w};
        #pragma unroll
        for (int i = 0; i < 4; i++)
            #pragma unroll
            for (int j = 0; j < 4; j++)
                acc[i][j] = fmaf(xs[i], ws[j], acc[i][j]);
    }
    #pragma unroll
    for (int i = 0; i < 4; i++) {
        int r = row0 + r0 + i;
        if (r < N)
            *(float4*)&Y[(size_t)r * COLS + c0] =
                make_float4(acc[i][0], acc[i][1], acc[i][2], acc[i][3]);
    }
}

// ---- node-centric aggregation: one wave per node, relu(agg + b) ----
template <int F>  // F=128: float2/lane; F=64: float/lane
__global__ __launch_bounds__(256) void agg_kernel(const float* __restrict__ H,
                                                  const int* __restrict__ row_ptr,
                                                  const int* __restrict__ csr_src,
                                                  const float* __restrict__ csr_w,
                                                  const float* __restrict__ dinv,
                                                  const float* __restrict__ bias,
                                                  float* __restrict__ out, int N) {
    int n = (blockIdx.x * blockDim.x + threadIdx.x) >> 6;
    int lane = threadIdx.x & 63;
    if (n >= N) return;

    float di = dinv[n];
    float wself = di * di;
    int e0 = row_ptr[n], e1 = row_ptr[n + 1];

    if constexpr (F == 128) {
        float2 hv = *(const float2*)&H[(size_t)n * 128 + lane * 2];
        float accx = wself * hv.x, accy = wself * hv.y;
        for (int base = e0; base < e1; base += 64) {
            int e = base + lane;
            int sv = 0; float wv = 0.0f;
            if (e < e1) { sv = csr_src[e]; wv = csr_w[e]; }
            int cnt = min(64, e1 - base);
            for (int j = 0; j < cnt; j++) {
                int s = __shfl(sv, j);
                float w = __shfl(wv, j);
                float2 v = *(const float2*)&H[(size_t)s * 128 + lane * 2];
                accx = fmaf(w, v.x, accx);
                accy = fmaf(w, v.y, accy);
            }
        }
        float ox = fmaxf(accx + bias[lane * 2], 0.0f);
        float oy = fmaxf(accy + bias[lane * 2 + 1], 0.0f);
        *(float2*)&out[(size_t)n * 128 + lane * 2] = make_float2(ox, oy);
    } else {
        float acc = wself * H[(size_t)n * F + lane];
        for (int base = e0; base < e1; base += 64) {
            int e = base + lane;
            int sv = 0; float wv = 0.0f;
            if (e < e1) { sv = csr_src[e]; wv = csr_w[e]; }
            int cnt = min(64, e1 - base);
            for (int j = 0; j < cnt; j++) {
                int s = __shfl(sv, j);
                float w = __shfl(wv, j);
                acc = fmaf(w, H[(size_t)s * F + lane], acc);
            }
        }
        out[(size_t)n * F + lane] = fmaxf(acc + bias[lane], 0.0f);
    }
}

extern "C" void kernel_launch(void* const* d_in, const int* in_sizes, int n_in,
                              void* d_out, int out_size, void* d_ws, size_t ws_size,
                              hipStream_t stream) {
    const float* x  = (const float*)d_in[0];
    const int*   ei = (const int*)d_in[1];
    const float* W1 = (const float*)d_in[2];
    const float* b1 = (const float*)d_in[3];
    const float* W2 = (const float*)d_in[4];
    const float* b2 = (const float*)d_in[5];
    float* out = (float*)d_out;

    const int HID  = in_sizes[3];          // 128
    const int F_IN = in_sizes[2] / HID;    // 128
    const int N    = in_sizes[0] / F_IN;   // 50000
    const int E    = in_sizes[1] / 2;      // 1.6M
    (void)n_in; (void)out_size; (void)ws_size;

    const int* src = ei;
    const int* dst = ei + E;

    // ---- carve workspace ----
    char* p = (char*)d_ws;
    auto carve = [&](size_t bytes) { void* q = (void*)p; p += (bytes + 255) & ~(size_t)255; return q; };
    int*   deg       = (int*)  carve((size_t)N * 4);
    float* dinv      = (float*)carve((size_t)N * 4);
    int*   row_ptr   = (int*)  carve((size_t)(N + 1) * 4);
    int*   cursor    = (int*)  carve((size_t)N * 4);
    int*   blockSums = (int*)  carve(4096);
    int*   csr_src   = (int*)  carve((size_t)E * 4);
    float* csr_w     = (float*)carve((size_t)E * 4);
    float* bufA      = (float*)carve((size_t)N * 128 * 4);  // gemm1 out / gemm2 out
    float* bufB      = (float*)carve((size_t)N * 128 * 4);  // h1 (post agg+relu)

    // ---- build normalized CSR (once, reused by both layers) ----
    hipMemsetAsync(deg, 0, (size_t)N * 4, stream);
    deg_kernel<<<(E + 255) / 256, 256, 0, stream>>>(dst, E, deg);
    dinv_kernel<<<(N + 255) / 256, 256, 0, stream>>>(deg, dinv, N);
    int numChunks = (N + 1023) / 1024;
    scan_partial<<<numChunks, 256, 0, stream>>>(deg, N, blockSums);
    scan_blocksums<<<1, 64, 0, stream>>>(blockSums, numChunks);
    scan_final<<<numChunks, 256, 0, stream>>>(deg, N, blockSums, row_ptr, cursor, E);
    fill_csr<<<(E + 255) / 256, 256, 0, stream>>>(src, dst, E, dinv, cursor, csr_src, csr_w);

    // ---- layer 1: bufA = x@W1 ; bufB = relu(agg(bufA) + b1) ----
    gemm_kernel<128><<<(N + 31) / 32, 256, 0, stream>>>(x, W1, bufA, N);
    agg_kernel<128><<<(N + 3) / 4, 256, 0, stream>>>(bufA, row_ptr, csr_src, csr_w, dinv, b1, bufB, N);

    // ---- layer 2: bufA = bufB@W2 ; out = relu(agg(bufA) + b2) ----
    gemm_kernel<64><<<(N + 63) / 64, 256, 0, stream>>>(bufB, W2, bufA, N);
    agg_kernel<64><<<(N + 3) / 4, 256, 0, stream>>>(bufA, row_ptr, csr_src, csr_w, dinv, b2, out, N);
}

// Round 2
// 504.232 us; speedup vs baseline: 1.1045x; 1.1045x over previous
//
#include <hip/hip_runtime.h>

// ---------------------------------------------------------------------------
// GCN 2-layer forward: out = relu(A_hat @ relu(A_hat @ (X W1) + b1) W2 + b2)
// A_hat = D^-1/2 (A + I) D^-1/2.
// Normalization folded: g = dinv[row] * (X@W); agg_n = dinv[n]*(g[n] + sum g[src]).
// CSR (by dst) holds ONLY src indices (4B/edge) -> halves scatter write traffic.
// ---------------------------------------------------------------------------

__global__ void deg_kernel(const int* __restrict__ dst, int E, int* __restrict__ deg) {
    int i = blockIdx.x * blockDim.x + threadIdx.x;
    if (i < E) atomicAdd(&deg[dst[i]], 1);
}

__global__ void dinv_kernel(const int* __restrict__ deg, float* __restrict__ dinv, int N) {
    int i = blockIdx.x * blockDim.x + threadIdx.x;
    if (i < N) dinv[i] = rsqrtf((float)(deg[i] + 1));  // +1 = self loop
}

// ---- exclusive scan of deg[N] -> row_ptr[N+1] (3 kernels) ----
__global__ void scan_partial(const int* __restrict__ deg, int N, int* __restrict__ blockSums) {
    __shared__ int sdata[256];
    int tid = threadIdx.x;
    int base = blockIdx.x * 1024;
    int sum = 0;
    for (int j = tid; j < 1024; j += 256) {
        int i = base + j;
        sum += (i < N) ? deg[i] : 0;
    }
    sdata[tid] = sum; __syncthreads();
    for (int off = 128; off > 0; off >>= 1) {
        if (tid < off) sdata[tid] += sdata[tid + off];
        __syncthreads();
    }
    if (tid == 0) blockSums[blockIdx.x] = sdata[0];
}

__global__ void scan_blocksums(int* __restrict__ blockSums, int n) {
    if (blockIdx.x == 0 && threadIdx.x == 0) {
        int acc = 0;
        for (int i = 0; i < n; i++) { int v = blockSums[i]; blockSums[i] = acc; acc += v; }
        blockSums[n] = acc;
    }
}

__global__ void scan_final(const int* __restrict__ deg, int N,
                           const int* __restrict__ blockSums,
                           int* __restrict__ row_ptr, int* __restrict__ cursor, int E) {
    __shared__ int sdata[256];
    int tid = threadIdx.x;
    int base = blockIdx.x * 1024;
    int carry = blockSums[blockIdx.x];
    int idx0 = base + tid * 4;
    int v[4]; int s = 0;
    #pragma unroll
    for (int q = 0; q < 4; q++) { int i = idx0 + q; v[q] = (i < N) ? deg[i] : 0; s += v[q]; }
    sdata[tid] = s; __syncthreads();
    for (int off = 1; off < 256; off <<= 1) {
        int t = (tid >= off) ? sdata[tid - off] : 0;
        __syncthreads();
        sdata[tid] += t;
        __syncthreads();
    }
    int excl = sdata[tid] - s + carry;
    #pragma unroll
    for (int q = 0; q < 4; q++) {
        int i = idx0 + q;
        if (i < N) { row_ptr[i] = excl; cursor[i] = excl; }
        excl += v[q];
    }
    if (blockIdx.x == 0 && tid == 0) row_ptr[N] = E;
}

__global__ void fill_csr(const int* __restrict__ src, const int* __restrict__ dst, int E,
                         int* __restrict__ cursor, int* __restrict__ csr_src) {
    int i = blockIdx.x * blockDim.x + threadIdx.x;
    if (i < E) {
        int d = dst[i];
        int pos = atomicAdd(&cursor[d], 1);
        csr_src[pos] = src[i];
    }
}

// ---- fp32 GEMM: Y[r,:] = dinv[r] * (X[r,:] @ W), 4x4 register tile ----
template <int COLS>
__global__ __launch_bounds__(256) void gemm_kernel(const float* __restrict__ X,
                                                   const float* __restrict__ W,
                                                   const float* __restrict__ dinv,
                                                   float* __restrict__ Y, int N) {
    constexpr int CT = COLS / 4;       // threads along cols
    constexpr int RT = 256 / CT;       // threads along rows
    constexpr int ROWS = RT * 4;       // rows per block
    constexpr int LDT = ROWS + 4;      // pad keeps 16B alignment + spreads banks
    __shared__ float xT[128 * LDT];    // x transposed: [k][r]

    int tid = threadIdx.x;
    int row0 = blockIdx.x * ROWS;
    int kk = tid & 127;
    for (int rr = tid >> 7; rr < ROWS; rr += 2) {
        int r = row0 + rr;
        xT[kk * LDT + rr] = (r < N) ? X[(size_t)r * 128 + kk] : 0.0f;
    }
    __syncthreads();

    int ct = tid % CT, rt = tid / CT;
    int c0 = ct * 4, r0 = rt * 4;
    float acc[4][4] = {};
    #pragma unroll 4
    for (int k = 0; k < 128; k++) {
        float4 xv = *(const float4*)&xT[k * LDT + r0];
        float4 wv = *(const float4*)&W[(size_t)k * COLS + c0];
        float xs[4] = {xv.x, xv.y, xv.z, xv.w};
        float ws[4] = {wv.x, wv.y, wv.z, wv.w};
        #pragma unroll
        for (int i = 0; i < 4; i++)
            #pragma unroll
            for (int j = 0; j < 4; j++)
                acc[i][j] = fmaf(xs[i], ws[j], acc[i][j]);
    }
    #pragma unroll
    for (int i = 0; i < 4; i++) {
        int r = row0 + r0 + i;
        if (r < N) {
            float sc = dinv[r];
            *(float4*)&Y[(size_t)r * COLS + c0] =
                make_float4(sc * acc[i][0], sc * acc[i][1], sc * acc[i][2], sc * acc[i][3]);
        }
    }
}

// ---- node-centric aggregation: one wave per node ----
// out_n = relu( dinv[n] * (G[n] + sum_{e in-edges} G[src_e]) + bias )
template <int F>  // F=128: float2/lane; F=64: float/lane
__global__ __launch_bounds__(256) void agg_kernel(const float* __restrict__ G,
                                                  const int* __restrict__ row_ptr,
                                                  const int* __restrict__ csr_src,
                                                  const float* __restrict__ dinv,
                                                  const float* __restrict__ bias,
                                                  float* __restrict__ out, int N) {
    int n = (blockIdx.x * blockDim.x + threadIdx.x) >> 6;
    int lane = threadIdx.x & 63;
    if (n >= N) return;

    float di = dinv[n];
    int e0 = row_ptr[n], e1 = row_ptr[n + 1];

    if constexpr (F == 128) {
        float2 hv = *(const float2*)&G[(size_t)n * 128 + lane * 2];
        float accx = hv.x, accy = hv.y;   // self-loop term (already dinv[n]-scaled)
        for (int base = e0; base < e1; base += 64) {
            int e = base + lane;
            int sv = (e < e1) ? csr_src[e] : 0;
            int cnt = min(64, e1 - base);
            int j = 0;
            for (; j + 4 <= cnt; j += 4) {
                int s0 = __shfl(sv, j), s1 = __shfl(sv, j + 1);
                int s2 = __shfl(sv, j + 2), s3 = __shfl(sv, j + 3);
                float2 v0 = *(const float2*)&G[(size_t)s0 * 128 + lane * 2];
                float2 v1 = *(const float2*)&G[(size_t)s1 * 128 + lane * 2];
                float2 v2 = *(const float2*)&G[(size_t)s2 * 128 + lane * 2];
                float2 v3 = *(const float2*)&G[(size_t)s3 * 128 + lane * 2];
                accx += (v0.x + v1.x) + (v2.x + v3.x);
                accy += (v0.y + v1.y) + (v2.y + v3.y);
            }
            for (; j < cnt; j++) {
                int s = __shfl(sv, j);
                float2 v = *(const float2*)&G[(size_t)s * 128 + lane * 2];
                accx += v.x; accy += v.y;
            }
        }
        float ox = fmaxf(fmaf(di, accx, bias[lane * 2]), 0.0f);
        float oy = fmaxf(fmaf(di, accy, bias[lane * 2 + 1]), 0.0f);
        *(float2*)&out[(size_t)n * 128 + lane * 2] = make_float2(ox, oy);
    } else {
        float acc = G[(size_t)n * F + lane];  // self-loop term
        for (int base = e0; base < e1; base += 64) {
            int e = base + lane;
            int sv = (e < e1) ? csr_src[e] : 0;
            int cnt = min(64, e1 - base);
            int j = 0;
            for (; j + 4 <= cnt; j += 4) {
                int s0 = __shfl(sv, j), s1 = __shfl(sv, j + 1);
                int s2 = __shfl(sv, j + 2), s3 = __shfl(sv, j + 3);
                float v0 = G[(size_t)s0 * F + lane];
                float v1 = G[(size_t)s1 * F + lane];
                float v2 = G[(size_t)s2 * F + lane];
                float v3 = G[(size_t)s3 * F + lane];
                acc += (v0 + v1) + (v2 + v3);
            }
            for (; j < cnt; j++) {
                int s = __shfl(sv, j);
                acc += G[(size_t)s * F + lane];
            }
        }
        out[(size_t)n * F + lane] = fmaxf(fmaf(di, acc, bias[lane]), 0.0f);
    }
}

extern "C" void kernel_launch(void* const* d_in, const int* in_sizes, int n_in,
                              void* d_out, int out_size, void* d_ws, size_t ws_size,
                              hipStream_t stream) {
    const float* x  = (const float*)d_in[0];
    const int*   ei = (const int*)d_in[1];
    const float* W1 = (const float*)d_in[2];
    const float* b1 = (const float*)d_in[3];
    const float* W2 = (const float*)d_in[4];
    const float* b2 = (const float*)d_in[5];
    float* out = (float*)d_out;

    const int HID  = in_sizes[3];          // 128
    const int F_IN = in_sizes[2] / HID;    // 128
    const int N    = in_sizes[0] / F_IN;   // 50000
    const int E    = in_sizes[1] / 2;      // 1.6M
    (void)n_in; (void)out_size; (void)ws_size;

    const int* src = ei;
    const int* dst = ei + E;

    // ---- carve workspace ----
    char* p = (char*)d_ws;
    auto carve = [&](size_t bytes) { void* q = (void*)p; p += (bytes + 255) & ~(size_t)255; return q; };
    int*   deg       = (int*)  carve((size_t)N * 4);
    float* dinv      = (float*)carve((size_t)N * 4);
    int*   row_ptr   = (int*)  carve((size_t)(N + 1) * 4);
    int*   cursor    = (int*)  carve((size_t)N * 4);
    int*   blockSums = (int*)  carve(4096);
    int*   csr_src   = (int*)  carve((size_t)E * 4);
    float* bufA      = (float*)carve((size_t)N * 128 * 4);  // gemm1 out / gemm2 out
    float* bufB      = (float*)carve((size_t)N * 128 * 4);  // h1 (post agg+relu)

    // ---- build normalized CSR (once, reused by both layers) ----
    hipMemsetAsync(deg, 0, (size_t)N * 4, stream);
    deg_kernel<<<(E + 255) / 256, 256, 0, stream>>>(dst, E, deg);
    dinv_kernel<<<(N + 255) / 256, 256, 0, stream>>>(deg, dinv, N);
    int numChunks = (N + 1023) / 1024;
    scan_partial<<<numChunks, 256, 0, stream>>>(deg, N, blockSums);
    scan_blocksums<<<1, 64, 0, stream>>>(blockSums, numChunks);
    scan_final<<<numChunks, 256, 0, stream>>>(deg, N, blockSums, row_ptr, cursor, E);
    fill_csr<<<(E + 255) / 256, 256, 0, stream>>>(src, dst, E, cursor, csr_src);

    // ---- layer 1: bufA = dinv*(x@W1) ; bufB = relu(dinv*agg + b1) ----
    gemm_kernel<128><<<(N + 31) / 32, 256, 0, stream>>>(x, W1, dinv, bufA, N);
    agg_kernel<128><<<(N + 3) / 4, 256, 0, stream>>>(bufA, row_ptr, csr_src, dinv, b1, bufB, N);

    // ---- layer 2: bufA = dinv*(bufB@W2) ; out = relu(dinv*agg + b2) ----
    gemm_kernel<64><<<(N + 63) / 64, 256, 0, stream>>>(bufB, W2, dinv, bufA, N);
    agg_kernel<64><<<(N + 3) / 4, 256, 0, stream>>>(bufA, row_ptr, csr_src, dinv, b2, out, N);
}

// Round 3
// 462.961 us; speedup vs baseline: 1.2030x; 1.0891x over previous
//
#include <hip/hip_runtime.h>

// ---------------------------------------------------------------------------
// GCN 2-layer forward: out = relu(A_hat @ relu(A_hat @ (X W1) + b1) W2 + b2)
// A_hat = D^-1/2 (A + I) D^-1/2.
// Normalization folded: g = dinv[row] * (X@W); agg_n = dinv[n]*(g[n] + sum g[src]).
// CSR (by dst) holds ONLY src indices (4B/edge). CSR fill is BANDED: 4 passes,
// each scattering into a ~1.6MB dst-range region that stays L2-resident
// (R2 showed unbanded scatter wrote back 64B/line per 4B store: 101MB HBM).
// ---------------------------------------------------------------------------

#define NBANDS 4

__global__ void deg_kernel(const int* __restrict__ dst, int E, int* __restrict__ deg) {
    int i = blockIdx.x * blockDim.x + threadIdx.x;
    if (i < E) atomicAdd(&deg[dst[i]], 1);
}

__global__ void dinv_kernel(const int* __restrict__ deg, float* __restrict__ dinv, int N) {
    int i = blockIdx.x * blockDim.x + threadIdx.x;
    if (i < N) dinv[i] = rsqrtf((float)(deg[i] + 1));  // +1 = self loop
}

// ---- exclusive scan of deg[N] -> row_ptr[N+1] (3 kernels) ----
__global__ void scan_partial(const int* __restrict__ deg, int N, int* __restrict__ blockSums) {
    __shared__ int sdata[256];
    int tid = threadIdx.x;
    int base = blockIdx.x * 1024;
    int sum = 0;
    for (int j = tid; j < 1024; j += 256) {
        int i = base + j;
        sum += (i < N) ? deg[i] : 0;
    }
    sdata[tid] = sum; __syncthreads();
    for (int off = 128; off > 0; off >>= 1) {
        if (tid < off) sdata[tid] += sdata[tid + off];
        __syncthreads();
    }
    if (tid == 0) blockSums[blockIdx.x] = sdata[0];
}

__global__ void scan_blocksums(int* __restrict__ blockSums, int n) {
    if (blockIdx.x == 0 && threadIdx.x == 0) {
        int acc = 0;
        for (int i = 0; i < n; i++) { int v = blockSums[i]; blockSums[i] = acc; acc += v; }
        blockSums[n] = acc;
    }
}

__global__ void scan_final(const int* __restrict__ deg, int N,
                           const int* __restrict__ blockSums,
                           int* __restrict__ row_ptr, int* __restrict__ cursor, int E) {
    __shared__ int sdata[256];
    int tid = threadIdx.x;
    int base = blockIdx.x * 1024;
    int carry = blockSums[blockIdx.x];
    int idx0 = base + tid * 4;
    int v[4]; int s = 0;
    #pragma unroll
    for (int q = 0; q < 4; q++) { int i = idx0 + q; v[q] = (i < N) ? deg[i] : 0; s += v[q]; }
    sdata[tid] = s; __syncthreads();
    for (int off = 1; off < 256; off <<= 1) {
        int t = (tid >= off) ? sdata[tid - off] : 0;
        __syncthreads();
        sdata[tid] += t;
        __syncthreads();
    }
    int excl = sdata[tid] - s + carry;
    #pragma unroll
    for (int q = 0; q < 4; q++) {
        int i = idx0 + q;
        if (i < N) { row_ptr[i] = excl; cursor[i] = excl; }
        excl += v[q];
    }
    if (blockIdx.x == 0 && tid == 0) row_ptr[N] = E;
}

// Banded CSR fill: band = blockIdx.y handles dst in [band*W, band*W+W).
// Scatter region per band ~1.6MB -> L2-resident -> full-line writebacks.
__global__ void fill_csr_banded(const int* __restrict__ src, const int* __restrict__ dst,
                                int E, int bandWidth,
                                int* __restrict__ cursor, int* __restrict__ csr_src) {
    int band = blockIdx.y;
    int lo = band * bandWidth, hi = lo + bandWidth;
    int i = blockIdx.x * blockDim.x + threadIdx.x;
    if (i < E) {
        int d = dst[i];
        if (d >= lo && d < hi) {
            int pos = atomicAdd(&cursor[d], 1);
            csr_src[pos] = src[i];
        }
    }
}

// ---- fp32 GEMM: Y[r,:] = dinv[r] * (X[r,:] @ W), 4x4 register tile ----
template <int COLS>
__global__ __launch_bounds__(256) void gemm_kernel(const float* __restrict__ X,
                                                   const float* __restrict__ W,
                                                   const float* __restrict__ dinv,
                                                   float* __restrict__ Y, int N) {
    constexpr int CT = COLS / 4;       // threads along cols
    constexpr int RT = 256 / CT;       // threads along rows
    constexpr int ROWS = RT * 4;       // rows per block
    constexpr int LDT = ROWS + 4;      // pad keeps 16B alignment + spreads banks
    __shared__ float xT[128 * LDT];    // x transposed: [k][r]

    int tid = threadIdx.x;
    int row0 = blockIdx.x * ROWS;
    int kk = tid & 127;
    for (int rr = tid >> 7; rr < ROWS; rr += 2) {
        int r = row0 + rr;
        xT[kk * LDT + rr] = (r < N) ? X[(size_t)r * 128 + kk] : 0.0f;
    }
    __syncthreads();

    int ct = tid % CT, rt = tid / CT;
    int c0 = ct * 4, r0 = rt * 4;
    float acc[4][4] = {};
    #pragma unroll 4
    for (int k = 0; k < 128; k++) {
        float4 xv = *(const float4*)&xT[k * LDT + r0];
        float4 wv = *(const float4*)&W[(size_t)k * COLS + c0];
        float xs[4] = {xv.x, xv.y, xv.z, xv.w};
        float ws[4] = {wv.x, wv.y, wv.z, wv.w};
        #pragma unroll
        for (int i = 0; i < 4; i++)
            #pragma unroll
            for (int j = 0; j < 4; j++)
                acc[i][j] = fmaf(xs[i], ws[j], acc[i][j]);
    }
    #pragma unroll
    for (int i = 0; i < 4; i++) {
        int r = row0 + r0 + i;
        if (r < N) {
            float sc = dinv[r];
            *(float4*)&Y[(size_t)r * COLS + c0] =
                make_float4(sc * acc[i][0], sc * acc[i][1], sc * acc[i][2], sc * acc[i][3]);
        }
    }
}

// ---- node-centric aggregation: one wave per node ----
// out_n = relu( dinv[n] * (G[n] + sum_{e in-edges} G[src_e]) + bias )
template <int F>  // F=128: float2/lane; F=64: float/lane
__global__ __launch_bounds__(256) void agg_kernel(const float* __restrict__ G,
                                                  const int* __restrict__ row_ptr,
                                                  const int* __restrict__ csr_src,
                                                  const float* __restrict__ dinv,
                                                  const float* __restrict__ bias,
                                                  float* __restrict__ out, int N) {
    int n = (blockIdx.x * blockDim.x + threadIdx.x) >> 6;
    int lane = threadIdx.x & 63;
    if (n >= N) return;

    float di = dinv[n];
    int e0 = row_ptr[n], e1 = row_ptr[n + 1];

    if constexpr (F == 128) {
        float2 hv = *(const float2*)&G[(size_t)n * 128 + lane * 2];
        float accx = hv.x, accy = hv.y;   // self-loop term (already dinv[n]-scaled)
        for (int base = e0; base < e1; base += 64) {
            int e = base + lane;
            int sv = (e < e1) ? csr_src[e] : 0;
            int cnt = min(64, e1 - base);
            int j = 0;
            for (; j + 8 <= cnt; j += 8) {
                int s0 = __shfl(sv, j),     s1 = __shfl(sv, j + 1);
                int s2 = __shfl(sv, j + 2), s3 = __shfl(sv, j + 3);
                int s4 = __shfl(sv, j + 4), s5 = __shfl(sv, j + 5);
                int s6 = __shfl(sv, j + 6), s7 = __shfl(sv, j + 7);
                float2 v0 = *(const float2*)&G[(size_t)s0 * 128 + lane * 2];
                float2 v1 = *(const float2*)&G[(size_t)s1 * 128 + lane * 2];
                float2 v2 = *(const float2*)&G[(size_t)s2 * 128 + lane * 2];
                float2 v3 = *(const float2*)&G[(size_t)s3 * 128 + lane * 2];
                float2 v4 = *(const float2*)&G[(size_t)s4 * 128 + lane * 2];
                float2 v5 = *(const float2*)&G[(size_t)s5 * 128 + lane * 2];
                float2 v6 = *(const float2*)&G[(size_t)s6 * 128 + lane * 2];
                float2 v7 = *(const float2*)&G[(size_t)s7 * 128 + lane * 2];
                accx += ((v0.x + v1.x) + (v2.x + v3.x)) + ((v4.x + v5.x) + (v6.x + v7.x));
                accy += ((v0.y + v1.y) + (v2.y + v3.y)) + ((v4.y + v5.y) + (v6.y + v7.y));
            }
            for (; j < cnt; j++) {
                int s = __shfl(sv, j);
                float2 v = *(const float2*)&G[(size_t)s * 128 + lane * 2];
                accx += v.x; accy += v.y;
            }
        }
        float ox = fmaxf(fmaf(di, accx, bias[lane * 2]), 0.0f);
        float oy = fmaxf(fmaf(di, accy, bias[lane * 2 + 1]), 0.0f);
        *(float2*)&out[(size_t)n * 128 + lane * 2] = make_float2(ox, oy);
    } else {
        float acc = G[(size_t)n * F + lane];  // self-loop term
        for (int base = e0; base < e1; base += 64) {
            int e = base + lane;
            int sv = (e < e1) ? csr_src[e] : 0;
            int cnt = min(64, e1 - base);
            int j = 0;
            for (; j + 8 <= cnt; j += 8) {
                int s0 = __shfl(sv, j),     s1 = __shfl(sv, j + 1);
                int s2 = __shfl(sv, j + 2), s3 = __shfl(sv, j + 3);
                int s4 = __shfl(sv, j + 4), s5 = __shfl(sv, j + 5);
                int s6 = __shfl(sv, j + 6), s7 = __shfl(sv, j + 7);
                float v0 = G[(size_t)s0 * F + lane];
                float v1 = G[(size_t)s1 * F + lane];
                float v2 = G[(size_t)s2 * F + lane];
                float v3 = G[(size_t)s3 * F + lane];
                float v4 = G[(size_t)s4 * F + lane];
                float v5 = G[(size_t)s5 * F + lane];
                float v6 = G[(size_t)s6 * F + lane];
                float v7 = G[(size_t)s7 * F + lane];
                acc += ((v0 + v1) + (v2 + v3)) + ((v4 + v5) + (v6 + v7));
            }
            for (; j < cnt; j++) {
                int s = __shfl(sv, j);
                acc += G[(size_t)s * F + lane];
            }
        }
        out[(size_t)n * F + lane] = fmaxf(fmaf(di, acc, bias[lane]), 0.0f);
    }
}

extern "C" void kernel_launch(void* const* d_in, const int* in_sizes, int n_in,
                              void* d_out, int out_size, void* d_ws, size_t ws_size,
                              hipStream_t stream) {
    const float* x  = (const float*)d_in[0];
    const int*   ei = (const int*)d_in[1];
    const float* W1 = (const float*)d_in[2];
    const float* b1 = (const float*)d_in[3];
    const float* W2 = (const float*)d_in[4];
    const float* b2 = (const float*)d_in[5];
    float* out = (float*)d_out;

    const int HID  = in_sizes[3];          // 128
    const int F_IN = in_sizes[2] / HID;    // 128
    const int N    = in_sizes[0] / F_IN;   // 50000
    const int E    = in_sizes[1] / 2;      // 1.6M
    (void)n_in; (void)out_size; (void)ws_size;

    const int* src = ei;
    const int* dst = ei + E;

    // ---- carve workspace ----
    char* p = (char*)d_ws;
    auto carve = [&](size_t bytes) { void* q = (void*)p; p += (bytes + 255) & ~(size_t)255; return q; };
    int*   deg       = (int*)  carve((size_t)N * 4);
    float* dinv      = (float*)carve((size_t)N * 4);
    int*   row_ptr   = (int*)  carve((size_t)(N + 1) * 4);
    int*   cursor    = (int*)  carve((size_t)N * 4);
    int*   blockSums = (int*)  carve(4096);
    int*   csr_src   = (int*)  carve((size_t)E * 4);
    float* bufA      = (float*)carve((size_t)N * 128 * 4);  // gemm1 out / gemm2 out
    float* bufB      = (float*)carve((size_t)N * 128 * 4);  // h1 (post agg+relu)

    // ---- build normalized CSR (once, reused by both layers) ----
    hipMemsetAsync(deg, 0, (size_t)N * 4, stream);
    deg_kernel<<<(E + 255) / 256, 256, 0, stream>>>(dst, E, deg);
    dinv_kernel<<<(N + 255) / 256, 256, 0, stream>>>(deg, dinv, N);
    int numChunks = (N + 1023) / 1024;
    scan_partial<<<numChunks, 256, 0, stream>>>(deg, N, blockSums);
    scan_blocksums<<<1, 64, 0, stream>>>(blockSums, numChunks);
    scan_final<<<numChunks, 256, 0, stream>>>(deg, N, blockSums, row_ptr, cursor, E);

    int bandWidth = (N + NBANDS - 1) / NBANDS;
    dim3 fillGrid((E + 255) / 256, NBANDS);
    fill_csr_banded<<<fillGrid, 256, 0, stream>>>(src, dst, E, bandWidth, cursor, csr_src);

    // ---- layer 1: bufA = dinv*(x@W1) ; bufB = relu(dinv*agg + b1) ----
    gemm_kernel<128><<<(N + 31) / 32, 256, 0, stream>>>(x, W1, dinv, bufA, N);
    agg_kernel<128><<<(N + 3) / 4, 256, 0, stream>>>(bufA, row_ptr, csr_src, dinv, b1, bufB, N);

    // ---- layer 2: bufA = dinv*(bufB@W2) ; out = relu(dinv*agg + b2) ----
    gemm_kernel<64><<<(N + 63) / 64, 256, 0, stream>>>(bufB, W2, dinv, bufA, N);
    agg_kernel<64><<<(N + 3) / 4, 256, 0, stream>>>(bufA, row_ptr, csr_src, dinv, b2, out, N);
}

// Round 4
// 394.392 us; speedup vs baseline: 1.4121x; 1.1739x over previous
//
#include <hip/hip_runtime.h>
#include <hip/hip_fp16.h>

// ---------------------------------------------------------------------------
// GCN 2-layer forward: out = relu(A_hat @ relu(A_hat @ (X W1) + b1) W2 + b2)
// A_hat = D^-1/2 (A + I) D^-1/2.
// Normalization folded: g = dinv[row] * (X@W); agg_n = dinv[n]*(g[n] + sum g[src]).
// Gather table G stored in FP16 (halves L2-miss traffic; rel err 2^-11 safe
// within 6e-3 threshold). CSR fill banded (4 passes, L2-resident scatter).
// ---------------------------------------------------------------------------

#define NBANDS 4

__global__ void deg_kernel(const int* __restrict__ dst, int E, int* __restrict__ deg) {
    int i = blockIdx.x * blockDim.x + threadIdx.x;
    if (i < E) atomicAdd(&deg[dst[i]], 1);
}

__global__ void dinv_kernel(const int* __restrict__ deg, float* __restrict__ dinv, int N) {
    int i = blockIdx.x * blockDim.x + threadIdx.x;
    if (i < N) dinv[i] = rsqrtf((float)(deg[i] + 1));  // +1 = self loop
}

// ---- exclusive scan of deg[N] -> row_ptr[N+1] (3 kernels) ----
__global__ void scan_partial(const int* __restrict__ deg, int N, int* __restrict__ blockSums) {
    __shared__ int sdata[256];
    int tid = threadIdx.x;
    int base = blockIdx.x * 1024;
    int sum = 0;
    for (int j = tid; j < 1024; j += 256) {
        int i = base + j;
        sum += (i < N) ? deg[i] : 0;
    }
    sdata[tid] = sum; __syncthreads();
    for (int off = 128; off > 0; off >>= 1) {
        if (tid < off) sdata[tid] += sdata[tid + off];
        __syncthreads();
    }
    if (tid == 0) blockSums[blockIdx.x] = sdata[0];
}

__global__ void scan_blocksums(int* __restrict__ blockSums, int n) {
    if (blockIdx.x == 0 && threadIdx.x == 0) {
        int acc = 0;
        for (int i = 0; i < n; i++) { int v = blockSums[i]; blockSums[i] = acc; acc += v; }
        blockSums[n] = acc;
    }
}

__global__ void scan_final(const int* __restrict__ deg, int N,
                           const int* __restrict__ blockSums,
                           int* __restrict__ row_ptr, int* __restrict__ cursor, int E) {
    __shared__ int sdata[256];
    int tid = threadIdx.x;
    int base = blockIdx.x * 1024;
    int carry = blockSums[blockIdx.x];
    int idx0 = base + tid * 4;
    int v[4]; int s = 0;
    #pragma unroll
    for (int q = 0; q < 4; q++) { int i = idx0 + q; v[q] = (i < N) ? deg[i] : 0; s += v[q]; }
    sdata[tid] = s; __syncthreads();
    for (int off = 1; off < 256; off <<= 1) {
        int t = (tid >= off) ? sdata[tid - off] : 0;
        __syncthreads();
        sdata[tid] += t;
        __syncthreads();
    }
    int excl = sdata[tid] - s + carry;
    #pragma unroll
    for (int q = 0; q < 4; q++) {
        int i = idx0 + q;
        if (i < N) { row_ptr[i] = excl; cursor[i] = excl; }
        excl += v[q];
    }
    if (blockIdx.x == 0 && tid == 0) row_ptr[N] = E;
}

// Banded CSR fill: band = blockIdx.y handles dst in [band*W, band*W+W).
__global__ void fill_csr_banded(const int* __restrict__ src, const int* __restrict__ dst,
                                int E, int bandWidth,
                                int* __restrict__ cursor, int* __restrict__ csr_src) {
    int band = blockIdx.y;
    int lo = band * bandWidth, hi = lo + bandWidth;
    int i = blockIdx.x * blockDim.x + threadIdx.x;
    if (i < E) {
        int d = dst[i];
        if (d >= lo && d < hi) {
            int pos = atomicAdd(&cursor[d], 1);
            csr_src[pos] = src[i];
        }
    }
}

// ---- fp32 GEMM: Y[r,:] = half( dinv[r] * (X[r,:] @ W) ), 4x4 register tile ----
template <int COLS>
__global__ __launch_bounds__(256) void gemm_kernel(const float* __restrict__ X,
                                                   const float* __restrict__ W,
                                                   const float* __restrict__ dinv,
                                                   __half* __restrict__ Y, int N) {
    constexpr int CT = COLS / 4;       // threads along cols
    constexpr int RT = 256 / CT;       // threads along rows
    constexpr int ROWS = RT * 4;       // rows per block
    constexpr int LDT = ROWS + 4;      // pad keeps 16B alignment + spreads banks
    __shared__ float xT[128 * LDT];    // x transposed: [k][r]

    int tid = threadIdx.x;
    int row0 = blockIdx.x * ROWS;
    int kk = tid & 127;
    for (int rr = tid >> 7; rr < ROWS; rr += 2) {
        int r = row0 + rr;
        xT[kk * LDT + rr] = (r < N) ? X[(size_t)r * 128 + kk] : 0.0f;
    }
    __syncthreads();

    int ct = tid % CT, rt = tid / CT;
    int c0 = ct * 4, r0 = rt * 4;
    float acc[4][4] = {};
    #pragma unroll 4
    for (int k = 0; k < 128; k++) {
        float4 xv = *(const float4*)&xT[k * LDT + r0];
        float4 wv = *(const float4*)&W[(size_t)k * COLS + c0];
        float xs[4] = {xv.x, xv.y, xv.z, xv.w};
        float ws[4] = {wv.x, wv.y, wv.z, wv.w};
        #pragma unroll
        for (int i = 0; i < 4; i++)
            #pragma unroll
            for (int j = 0; j < 4; j++)
                acc[i][j] = fmaf(xs[i], ws[j], acc[i][j]);
    }
    #pragma unroll
    for (int i = 0; i < 4; i++) {
        int r = row0 + r0 + i;
        if (r < N) {
            float sc = dinv[r];
            __half2 p0 = __floats2half2_rn(sc * acc[i][0], sc * acc[i][1]);
            __half2 p1 = __floats2half2_rn(sc * acc[i][2], sc * acc[i][3]);
            *(__half2*)&Y[(size_t)r * COLS + c0]     = p0;
            *(__half2*)&Y[(size_t)r * COLS + c0 + 2] = p1;
        }
    }
}

// ---- aggregation F=128: one wave per node, lane owns 2 features (half2) ----
__global__ __launch_bounds__(256) void agg_kernel_128(const __half* __restrict__ G,
                                                      const int* __restrict__ row_ptr,
                                                      const int* __restrict__ csr_src,
                                                      const float* __restrict__ dinv,
                                                      const float* __restrict__ bias,
                                                      float* __restrict__ out, int N) {
    int n = (blockIdx.x * blockDim.x + threadIdx.x) >> 6;
    int lane = threadIdx.x & 63;
    if (n >= N) return;

    float di = dinv[n];
    int e0 = row_ptr[n], e1 = row_ptr[n + 1];

    float2 self = __half22float2(*(const __half2*)&G[(size_t)n * 128 + lane * 2]);
    float accx = self.x, accy = self.y;
    for (int base = e0; base < e1; base += 64) {
        int e = base + lane;
        int sv = (e < e1) ? csr_src[e] : 0;
        int cnt = min(64, e1 - base);
        int j = 0;
        for (; j + 8 <= cnt; j += 8) {
            int s0 = __shfl(sv, j),     s1 = __shfl(sv, j + 1);
            int s2 = __shfl(sv, j + 2), s3 = __shfl(sv, j + 3);
            int s4 = __shfl(sv, j + 4), s5 = __shfl(sv, j + 5);
            int s6 = __shfl(sv, j + 6), s7 = __shfl(sv, j + 7);
            float2 v0 = __half22float2(*(const __half2*)&G[(size_t)s0 * 128 + lane * 2]);
            float2 v1 = __half22float2(*(const __half2*)&G[(size_t)s1 * 128 + lane * 2]);
            float2 v2 = __half22float2(*(const __half2*)&G[(size_t)s2 * 128 + lane * 2]);
            float2 v3 = __half22float2(*(const __half2*)&G[(size_t)s3 * 128 + lane * 2]);
            float2 v4 = __half22float2(*(const __half2*)&G[(size_t)s4 * 128 + lane * 2]);
            float2 v5 = __half22float2(*(const __half2*)&G[(size_t)s5 * 128 + lane * 2]);
            float2 v6 = __half22float2(*(const __half2*)&G[(size_t)s6 * 128 + lane * 2]);
            float2 v7 = __half22float2(*(const __half2*)&G[(size_t)s7 * 128 + lane * 2]);
            accx += ((v0.x + v1.x) + (v2.x + v3.x)) + ((v4.x + v5.x) + (v6.x + v7.x));
            accy += ((v0.y + v1.y) + (v2.y + v3.y)) + ((v4.y + v5.y) + (v6.y + v7.y));
        }
        for (; j < cnt; j++) {
            int s = __shfl(sv, j);
            float2 v = __half22float2(*(const __half2*)&G[(size_t)s * 128 + lane * 2]);
            accx += v.x; accy += v.y;
        }
    }
    float ox = fmaxf(fmaf(di, accx, bias[lane * 2]), 0.0f);
    float oy = fmaxf(fmaf(di, accy, bias[lane * 2 + 1]), 0.0f);
    *(float2*)&out[(size_t)n * 128 + lane * 2] = make_float2(ox, oy);
}

// ---- aggregation F=64: HALF-wave (32 lanes) per node, lane owns 2 features ----
__global__ __launch_bounds__(256) void agg_kernel_64(const __half* __restrict__ G,
                                                     const int* __restrict__ row_ptr,
                                                     const int* __restrict__ csr_src,
                                                     const float* __restrict__ dinv,
                                                     const float* __restrict__ bias,
                                                     float* __restrict__ out, int N) {
    int n = (blockIdx.x * blockDim.x + threadIdx.x) >> 5;
    int l = threadIdx.x & 31;
    if (n >= N) return;

    float di = dinv[n];
    int e0 = row_ptr[n], e1 = row_ptr[n + 1];

    float2 self = __half22float2(*(const __half2*)&G[(size_t)n * 64 + l * 2]);
    float accx = self.x, accy = self.y;
    for (int base = e0; base < e1; base += 32) {
        int e = base + l;
        int sv = (e < e1) ? csr_src[e] : 0;
        int cnt = min(32, e1 - base);
        int j = 0;
        for (; j + 8 <= cnt; j += 8) {
            int s0 = __shfl(sv, j, 32),     s1 = __shfl(sv, j + 1, 32);
            int s2 = __shfl(sv, j + 2, 32), s3 = __shfl(sv, j + 3, 32);
            int s4 = __shfl(sv, j + 4, 32), s5 = __shfl(sv, j + 5, 32);
            int s6 = __shfl(sv, j + 6, 32), s7 = __shfl(sv, j + 7, 32);
            float2 v0 = __half22float2(*(const __half2*)&G[(size_t)s0 * 64 + l * 2]);
            float2 v1 = __half22float2(*(const __half2*)&G[(size_t)s1 * 64 + l * 2]);
            float2 v2 = __half22float2(*(const __half2*)&G[(size_t)s2 * 64 + l * 2]);
            float2 v3 = __half22float2(*(const __half2*)&G[(size_t)s3 * 64 + l * 2]);
            float2 v4 = __half22float2(*(const __half2*)&G[(size_t)s4 * 64 + l * 2]);
            float2 v5 = __half22float2(*(const __half2*)&G[(size_t)s5 * 64 + l * 2]);
            float2 v6 = __half22float2(*(const __half2*)&G[(size_t)s6 * 64 + l * 2]);
            float2 v7 = __half22float2(*(const __half2*)&G[(size_t)s7 * 64 + l * 2]);
            accx += ((v0.x + v1.x) + (v2.x + v3.x)) + ((v4.x + v5.x) + (v6.x + v7.x));
            accy += ((v0.y + v1.y) + (v2.y + v3.y)) + ((v4.y + v5.y) + (v6.y + v7.y));
        }
        for (; j < cnt; j++) {
            int s = __shfl(sv, j, 32);
            float2 v = __half22float2(*(const __half2*)&G[(size_t)s * 64 + l * 2]);
            accx += v.x; accy += v.y;
        }
    }
    float ox = fmaxf(fmaf(di, accx, bias[l * 2]), 0.0f);
    float oy = fmaxf(fmaf(di, accy, bias[l * 2 + 1]), 0.0f);
    *(float2*)&out[(size_t)n * 64 + l * 2] = make_float2(ox, oy);
}

extern "C" void kernel_launch(void* const* d_in, const int* in_sizes, int n_in,
                              void* d_out, int out_size, void* d_ws, size_t ws_size,
                              hipStream_t stream) {
    const float* x  = (const float*)d_in[0];
    const int*   ei = (const int*)d_in[1];
    const float* W1 = (const float*)d_in[2];
    const float* b1 = (const float*)d_in[3];
    const float* W2 = (const float*)d_in[4];
    const float* b2 = (const float*)d_in[5];
    float* out = (float*)d_out;

    const int HID  = in_sizes[3];          // 128
    const int F_IN = in_sizes[2] / HID;    // 128
    const int N    = in_sizes[0] / F_IN;   // 50000
    const int E    = in_sizes[1] / 2;      // 1.6M
    (void)n_in; (void)out_size; (void)ws_size;

    const int* src = ei;
    const int* dst = ei + E;

    // ---- carve workspace ----
    char* p = (char*)d_ws;
    auto carve = [&](size_t bytes) { void* q = (void*)p; p += (bytes + 255) & ~(size_t)255; return q; };
    int*    deg       = (int*)   carve((size_t)N * 4);
    float*  dinv      = (float*) carve((size_t)N * 4);
    int*    row_ptr   = (int*)   carve((size_t)(N + 1) * 4);
    int*    cursor    = (int*)   carve((size_t)N * 4);
    int*    blockSums = (int*)   carve(4096);
    int*    csr_src   = (int*)   carve((size_t)E * 4);
    __half* bufG      = (__half*)carve((size_t)N * 128 * 2);  // fp16 gather table
    float*  bufB      = (float*) carve((size_t)N * 128 * 4);  // h1 (post agg+relu, fp32)

    // ---- build normalized CSR (once, reused by both layers) ----
    hipMemsetAsync(deg, 0, (size_t)N * 4, stream);
    deg_kernel<<<(E + 255) / 256, 256, 0, stream>>>(dst, E, deg);
    dinv_kernel<<<(N + 255) / 256, 256, 0, stream>>>(deg, dinv, N);
    int numChunks = (N + 1023) / 1024;
    scan_partial<<<numChunks, 256, 0, stream>>>(deg, N, blockSums);
    scan_blocksums<<<1, 64, 0, stream>>>(blockSums, numChunks);
    scan_final<<<numChunks, 256, 0, stream>>>(deg, N, blockSums, row_ptr, cursor, E);

    int bandWidth = (N + NBANDS - 1) / NBANDS;
    dim3 fillGrid((E + 255) / 256, NBANDS);
    fill_csr_banded<<<fillGrid, 256, 0, stream>>>(src, dst, E, bandWidth, cursor, csr_src);

    // ---- layer 1: bufG = half(dinv*(x@W1)) ; bufB = relu(dinv*agg + b1) ----
    gemm_kernel<128><<<(N + 31) / 32, 256, 0, stream>>>(x, W1, dinv, bufG, N);
    agg_kernel_128<<<(N + 3) / 4, 256, 0, stream>>>(bufG, row_ptr, csr_src, dinv, b1, bufB, N);

    // ---- layer 2: bufG = half(dinv*(bufB@W2)) ; out = relu(dinv*agg + b2) ----
    gemm_kernel<64><<<(N + 63) / 64, 256, 0, stream>>>(bufB, W2, dinv, bufG, N);
    agg_kernel_64<<<(N + 7) / 8, 256, 0, stream>>>(bufG, row_ptr, csr_src, dinv, b2, out, N);
}

// Round 5
// 382.075 us; speedup vs baseline: 1.4576x; 1.0322x over previous
//
#include <hip/hip_runtime.h>
#include <hip/hip_fp16.h>

// ---------------------------------------------------------------------------
// GCN 2-layer forward: out = relu(A_hat @ relu(A_hat @ (X W1) + b1) W2 + b2)
// A_hat = D^-1/2 (A + I) D^-1/2.
// Normalization folded: g = dinv[row] * (X@W); agg_n = dinv[n]*(g[n] + sum g[src]).
// Gather table G stored in FP16. CSR fill is XCD-ALIGNED banded: 8 bands,
// band = blockIdx.x with grid (8, E/256) -> linear%8 == band -> all writers of
// a band land on one XCD (round-robin heuristic), so its 800KB scatter region
// stays in THAT XCD's L2 and each line is written back once (R4 showed 8
// per-XCD partial-dirty copies -> 7x write amplification without this).
// ---------------------------------------------------------------------------

#define NBANDS 8

__global__ void deg_kernel(const int* __restrict__ dst, int E, int* __restrict__ deg) {
    int i = blockIdx.x * blockDim.x + threadIdx.x;
    if (i < E) atomicAdd(&deg[dst[i]], 1);
}

__global__ void dinv_kernel(const int* __restrict__ deg, float* __restrict__ dinv, int N) {
    int i = blockIdx.x * blockDim.x + threadIdx.x;
    if (i < N) dinv[i] = rsqrtf((float)(deg[i] + 1));  // +1 = self loop
}

// ---- exclusive scan of deg[N] -> row_ptr[N+1] (3 kernels) ----
__global__ void scan_partial(const int* __restrict__ deg, int N, int* __restrict__ blockSums) {
    __shared__ int sdata[256];
    int tid = threadIdx.x;
    int base = blockIdx.x * 1024;
    int sum = 0;
    for (int j = tid; j < 1024; j += 256) {
        int i = base + j;
        sum += (i < N) ? deg[i] : 0;
    }
    sdata[tid] = sum; __syncthreads();
    for (int off = 128; off > 0; off >>= 1) {
        if (tid < off) sdata[tid] += sdata[tid + off];
        __syncthreads();
    }
    if (tid == 0) blockSums[blockIdx.x] = sdata[0];
}

__global__ void scan_blocksums(int* __restrict__ blockSums, int n) {
    if (blockIdx.x == 0 && threadIdx.x == 0) {
        int acc = 0;
        for (int i = 0; i < n; i++) { int v = blockSums[i]; blockSums[i] = acc; acc += v; }
        blockSums[n] = acc;
    }
}

__global__ void scan_final(const int* __restrict__ deg, int N,
                           const int* __restrict__ blockSums,
                           int* __restrict__ row_ptr, int* __restrict__ cursor, int E) {
    __shared__ int sdata[256];
    int tid = threadIdx.x;
    int base = blockIdx.x * 1024;
    int carry = blockSums[blockIdx.x];
    int idx0 = base + tid * 4;
    int v[4]; int s = 0;
    #pragma unroll
    for (int q = 0; q < 4; q++) { int i = idx0 + q; v[q] = (i < N) ? deg[i] : 0; s += v[q]; }
    sdata[tid] = s; __syncthreads();
    for (int off = 1; off < 256; off <<= 1) {
        int t = (tid >= off) ? sdata[tid - off] : 0;
        __syncthreads();
        sdata[tid] += t;
        __syncthreads();
    }
    int excl = sdata[tid] - s + carry;
    #pragma unroll
    for (int q = 0; q < 4; q++) {
        int i = idx0 + q;
        if (i < N) { row_ptr[i] = excl; cursor[i] = excl; }
        excl += v[q];
    }
    if (blockIdx.x == 0 && tid == 0) row_ptr[N] = E;
}

// XCD-aligned banded CSR fill: band = blockIdx.x (grid.x == NBANDS == #XCDs),
// chunk = blockIdx.y. Linearized block id = band + NBANDS*chunk, and blocks are
// distributed round-robin over XCDs, so band k's scatter stays on XCD k.
__global__ void fill_csr_banded(const int* __restrict__ src, const int* __restrict__ dst,
                                int E, int bandWidth,
                                int* __restrict__ cursor, int* __restrict__ csr_src) {
    int band = blockIdx.x;
    int lo = band * bandWidth, hi = lo + bandWidth;
    int i = blockIdx.y * blockDim.x + threadIdx.x;
    if (i < E) {
        int d = dst[i];
        if (d >= lo && d < hi) {
            int pos = atomicAdd(&cursor[d], 1);
            csr_src[pos] = src[i];
        }
    }
}

// ---- fp32 GEMM: Y[r,:] = half( dinv[r] * (X[r,:] @ W) ), 4x4 register tile ----
template <int COLS>
__global__ __launch_bounds__(256) void gemm_kernel(const float* __restrict__ X,
                                                   const float* __restrict__ W,
                                                   const float* __restrict__ dinv,
                                                   __half* __restrict__ Y, int N) {
    constexpr int CT = COLS / 4;       // threads along cols
    constexpr int RT = 256 / CT;       // threads along rows
    constexpr int ROWS = RT * 4;       // rows per block
    constexpr int LDT = ROWS + 4;      // pad keeps 16B alignment + spreads banks
    __shared__ float xT[128 * LDT];    // x transposed: [k][r]

    int tid = threadIdx.x;
    int row0 = blockIdx.x * ROWS;
    int kk = tid & 127;
    for (int rr = tid >> 7; rr < ROWS; rr += 2) {
        int r = row0 + rr;
        xT[kk * LDT + rr] = (r < N) ? X[(size_t)r * 128 + kk] : 0.0f;
    }
    __syncthreads();

    int ct = tid % CT, rt = tid / CT;
    int c0 = ct * 4, r0 = rt * 4;
    float acc[4][4] = {};
    #pragma unroll 4
    for (int k = 0; k < 128; k++) {
        float4 xv = *(const float4*)&xT[k * LDT + r0];
        float4 wv = *(const float4*)&W[(size_t)k * COLS + c0];
        float xs[4] = {xv.x, xv.y, xv.z, xv.w};
        float ws[4] = {wv.x, wv.y, wv.z, wv.w};
        #pragma unroll
        for (int i = 0; i < 4; i++)
            #pragma unroll
            for (int j = 0; j < 4; j++)
                acc[i][j] = fmaf(xs[i], ws[j], acc[i][j]);
    }
    #pragma unroll
    for (int i = 0; i < 4; i++) {
        int r = row0 + r0 + i;
        if (r < N) {
            float sc = dinv[r];
            __half2 p0 = __floats2half2_rn(sc * acc[i][0], sc * acc[i][1]);
            __half2 p1 = __floats2half2_rn(sc * acc[i][2], sc * acc[i][3]);
            *(__half2*)&Y[(size_t)r * COLS + c0]     = p0;
            *(__half2*)&Y[(size_t)r * COLS + c0 + 2] = p1;
        }
    }
}

// ---- aggregation F=128: one wave per node, lane owns 2 features (half2) ----
__global__ __launch_bounds__(256) void agg_kernel_128(const __half* __restrict__ G,
                                                      const int* __restrict__ row_ptr,
                                                      const int* __restrict__ csr_src,
                                                      const float* __restrict__ dinv,
                                                      const float* __restrict__ bias,
                                                      float* __restrict__ out, int N) {
    int n = (blockIdx.x * blockDim.x + threadIdx.x) >> 6;
    int lane = threadIdx.x & 63;
    if (n >= N) return;

    float di = dinv[n];
    int e0 = row_ptr[n], e1 = row_ptr[n + 1];

    float2 self = __half22float2(*(const __half2*)&G[(size_t)n * 128 + lane * 2]);
    float accx = self.x, accy = self.y;
    for (int base = e0; base < e1; base += 64) {
        int e = base + lane;
        int sv = (e < e1) ? csr_src[e] : 0;
        int cnt = min(64, e1 - base);
        int j = 0;
        for (; j + 8 <= cnt; j += 8) {
            int s0 = __shfl(sv, j),     s1 = __shfl(sv, j + 1);
            int s2 = __shfl(sv, j + 2), s3 = __shfl(sv, j + 3);
            int s4 = __shfl(sv, j + 4), s5 = __shfl(sv, j + 5);
            int s6 = __shfl(sv, j + 6), s7 = __shfl(sv, j + 7);
            float2 v0 = __half22float2(*(const __half2*)&G[(size_t)s0 * 128 + lane * 2]);
            float2 v1 = __half22float2(*(const __half2*)&G[(size_t)s1 * 128 + lane * 2]);
            float2 v2 = __half22float2(*(const __half2*)&G[(size_t)s2 * 128 + lane * 2]);
            float2 v3 = __half22float2(*(const __half2*)&G[(size_t)s3 * 128 + lane * 2]);
            float2 v4 = __half22float2(*(const __half2*)&G[(size_t)s4 * 128 + lane * 2]);
            float2 v5 = __half22float2(*(const __half2*)&G[(size_t)s5 * 128 + lane * 2]);
            float2 v6 = __half22float2(*(const __half2*)&G[(size_t)s6 * 128 + lane * 2]);
            float2 v7 = __half22float2(*(const __half2*)&G[(size_t)s7 * 128 + lane * 2]);
            accx += ((v0.x + v1.x) + (v2.x + v3.x)) + ((v4.x + v5.x) + (v6.x + v7.x));
            accy += ((v0.y + v1.y) + (v2.y + v3.y)) + ((v4.y + v5.y) + (v6.y + v7.y));
        }
        for (; j < cnt; j++) {
            int s = __shfl(sv, j);
            float2 v = __half22float2(*(const __half2*)&G[(size_t)s * 128 + lane * 2]);
            accx += v.x; accy += v.y;
        }
    }
    float ox = fmaxf(fmaf(di, accx, bias[lane * 2]), 0.0f);
    float oy = fmaxf(fmaf(di, accy, bias[lane * 2 + 1]), 0.0f);
    *(float2*)&out[(size_t)n * 128 + lane * 2] = make_float2(ox, oy);
}

// ---- aggregation F=64: HALF-wave (32 lanes) per node, lane owns 2 features ----
__global__ __launch_bounds__(256) void agg_kernel_64(const __half* __restrict__ G,
                                                     const int* __restrict__ row_ptr,
                                                     const int* __restrict__ csr_src,
                                                     const float* __restrict__ dinv,
                                                     const float* __restrict__ bias,
                                                     float* __restrict__ out, int N) {
    int n = (blockIdx.x * blockDim.x + threadIdx.x) >> 5;
    int l = threadIdx.x & 31;
    if (n >= N) return;

    float di = dinv[n];
    int e0 = row_ptr[n], e1 = row_ptr[n + 1];

    float2 self = __half22float2(*(const __half2*)&G[(size_t)n * 64 + l * 2]);
    float accx = self.x, accy = self.y;
    for (int base = e0; base < e1; base += 32) {
        int e = base + l;
        int sv = (e < e1) ? csr_src[e] : 0;
        int cnt = min(32, e1 - base);
        int j = 0;
        for (; j + 8 <= cnt; j += 8) {
            int s0 = __shfl(sv, j, 32),     s1 = __shfl(sv, j + 1, 32);
            int s2 = __shfl(sv, j + 2, 32), s3 = __shfl(sv, j + 3, 32);
            int s4 = __shfl(sv, j + 4, 32), s5 = __shfl(sv, j + 5, 32);
            int s6 = __shfl(sv, j + 6, 32), s7 = __shfl(sv, j + 7, 32);
            float2 v0 = __half22float2(*(const __half2*)&G[(size_t)s0 * 64 + l * 2]);
            float2 v1 = __half22float2(*(const __half2*)&G[(size_t)s1 * 64 + l * 2]);
            float2 v2 = __half22float2(*(const __half2*)&G[(size_t)s2 * 64 + l * 2]);
            float2 v3 = __half22float2(*(const __half2*)&G[(size_t)s3 * 64 + l * 2]);
            float2 v4 = __half22float2(*(const __half2*)&G[(size_t)s4 * 64 + l * 2]);
            float2 v5 = __half22float2(*(const __half2*)&G[(size_t)s5 * 64 + l * 2]);
            float2 v6 = __half22float2(*(const __half2*)&G[(size_t)s6 * 64 + l * 2]);
            float2 v7 = __half22float2(*(const __half2*)&G[(size_t)s7 * 64 + l * 2]);
            accx += ((v0.x + v1.x) + (v2.x + v3.x)) + ((v4.x + v5.x) + (v6.x + v7.x));
            accy += ((v0.y + v1.y) + (v2.y + v3.y)) + ((v4.y + v5.y) + (v6.y + v7.y));
        }
        for (; j < cnt; j++) {
            int s = __shfl(sv, j, 32);
            float2 v = __half22float2(*(const __half2*)&G[(size_t)s * 64 + l * 2]);
            accx += v.x; accy += v.y;
        }
    }
    float ox = fmaxf(fmaf(di, accx, bias[l * 2]), 0.0f);
    float oy = fmaxf(fmaf(di, accy, bias[l * 2 + 1]), 0.0f);
    *(float2*)&out[(size_t)n * 64 + l * 2] = make_float2(ox, oy);
}

extern "C" void kernel_launch(void* const* d_in, const int* in_sizes, int n_in,
                              void* d_out, int out_size, void* d_ws, size_t ws_size,
                              hipStream_t stream) {
    const float* x  = (const float*)d_in[0];
    const int*   ei = (const int*)d_in[1];
    const float* W1 = (const float*)d_in[2];
    const float* b1 = (const float*)d_in[3];
    const float* W2 = (const float*)d_in[4];
    const float* b2 = (const float*)d_in[5];
    float* out = (float*)d_out;

    const int HID  = in_sizes[3];          // 128
    const int F_IN = in_sizes[2] / HID;    // 128
    const int N    = in_sizes[0] / F_IN;   // 50000
    const int E    = in_sizes[1] / 2;      // 1.6M
    (void)n_in; (void)out_size; (void)ws_size;

    const int* src = ei;
    const int* dst = ei + E;

    // ---- carve workspace ----
    char* p = (char*)d_ws;
    auto carve = [&](size_t bytes) { void* q = (void*)p; p += (bytes + 255) & ~(size_t)255; return q; };
    int*    deg       = (int*)   carve((size_t)N * 4);
    float*  dinv      = (float*) carve((size_t)N * 4);
    int*    row_ptr   = (int*)   carve((size_t)(N + 1) * 4);
    int*    cursor    = (int*)   carve((size_t)N * 4);
    int*    blockSums = (int*)   carve(4096);
    int*    csr_src   = (int*)   carve((size_t)E * 4);
    __half* bufG      = (__half*)carve((size_t)N * 128 * 2);  // fp16 gather table
    float*  bufB      = (float*) carve((size_t)N * 128 * 4);  // h1 (post agg+relu, fp32)

    // ---- build normalized CSR (once, reused by both layers) ----
    hipMemsetAsync(deg, 0, (size_t)N * 4, stream);
    deg_kernel<<<(E + 255) / 256, 256, 0, stream>>>(dst, E, deg);
    dinv_kernel<<<(N + 255) / 256, 256, 0, stream>>>(deg, dinv, N);
    int numChunks = (N + 1023) / 1024;
    scan_partial<<<numChunks, 256, 0, stream>>>(deg, N, blockSums);
    scan_blocksums<<<1, 64, 0, stream>>>(blockSums, numChunks);
    scan_final<<<numChunks, 256, 0, stream>>>(deg, N, blockSums, row_ptr, cursor, E);

    int bandWidth = (N + NBANDS - 1) / NBANDS;
    dim3 fillGrid(NBANDS, (E + 255) / 256);   // x = band (-> XCD), y = edge chunk
    fill_csr_banded<<<fillGrid, 256, 0, stream>>>(src, dst, E, bandWidth, cursor, csr_src);

    // ---- layer 1: bufG = half(dinv*(x@W1)) ; bufB = relu(dinv*agg + b1) ----
    gemm_kernel<128><<<(N + 31) / 32, 256, 0, stream>>>(x, W1, dinv, bufG, N);
    agg_kernel_128<<<(N + 3) / 4, 256, 0, stream>>>(bufG, row_ptr, csr_src, dinv, b1, bufB, N);

    // ---- layer 2: bufG = half(dinv*(bufB@W2)) ; out = relu(dinv*agg + b2) ----
    gemm_kernel<64><<<(N + 63) / 64, 256, 0, stream>>>(bufB, W2, dinv, bufG, N);
    agg_kernel_64<<<(N + 7) / 8, 256, 0, stream>>>(bufG, row_ptr, csr_src, dinv, b2, out, N);
}